// Round 1
// baseline (2223.105 us; speedup 1.0000x reference)
//
#include <hip/hip_runtime.h>
#include <hip/hip_bf16.h>
#include <cstdint>
#include <cstddef>

// Problem constants (from reference): B=1024, S=512, F=18, H=64, O=15
#define B_SZ  1024
#define S_LEN 512
#define NH    64
#define NG    256   // 4*H gate rows

// Fast, overflow-safe activations (monotone saturation at +-inf, no NaN):
__device__ __forceinline__ float sigmoid_f(float x) {
    // 1/(1+exp(-x)); exp via v_exp-based __expf, div via fast divide.
    return __fdividef(1.0f, 1.0f + __expf(-x));
}
__device__ __forceinline__ float tanh_f(float x) {
    // tanh(x) = 1 - 2/(exp(2x)+1); x->+inf: exp->inf -> 1; x->-inf: -> -1.
    return 1.0f - __fdividef(2.0f, __expf(2.0f * x) + 1.0f);
}

// One LSTM layer, persistent-weights-in-registers scan.
//  - grid = B/R blocks, block = 256 threads (= 4 waves).
//  - Thread j owns gate-row j of [W_ih | W_hh] (K = IN+64 fp32 weights in VGPRs).
//  - Per step: input vector [x_t | h_{t-1}] per row sits in LDS; all threads
//    read it as broadcast float4 (same-address -> conflict-free) and FMA into
//    their gate accumulator. Activation is wave-uniform (gate = j>>6).
//  - Second role: thread (r2 = j>>6 < R, jj = j&63) owns cell state c[row][jj]
//    in a register across all 512 steps.
template<int IN, int R>
__global__ __launch_bounds__(256, 2) void lstm_layer_kernel(
    const float* __restrict__ xin,    // [B][S][IN]
    const float* __restrict__ W_ih,   // [256][IN]
    const float* __restrict__ W_hh,   // [256][64]
    const float* __restrict__ b_ih,   // [256]
    const float* __restrict__ b_hh,   // [256]
    float* __restrict__ h_all,        // [B][S][64] or nullptr
    float* __restrict__ h_last)       // [B][64]    or nullptr
{
    constexpr int K  = IN + NH;
    constexpr int KP = (K + 15) & ~15;   // pad K to x16 floats (16B-aligned rows)
    __shared__ float in_lds[R][KP];      // [x_t (IN) | h_prev (64) | zero pad]
    __shared__ float g_lds[R][NG];       // activated gates

    const int j  = threadIdx.x;          // gate row 0..255
    const int b0 = blockIdx.x * R;       // first batch row of this block
    const int r2 = j >> 6;               // cell-update role: row index
    const int jj = j & 63;               // cell-update role: feature index

    // Persistent weights in registers, concatenated [W_ih row | W_hh row | 0s].
    float w[KP];
    #pragma unroll
    for (int k = 0; k < IN; ++k) w[k] = W_ih[j * IN + k];
    #pragma unroll
    for (int k = 0; k < NH; ++k) w[IN + k] = W_hh[j * NH + k];
    #pragma unroll
    for (int k = K; k < KP; ++k) w[k] = 0.0f;

    const float bias = b_ih[j] + b_hh[j];

    // Zero all of in_lds: h-part = h0 = 0, pad stays 0 for the whole kernel.
    for (int t = j; t < R * KP; t += NG) ((float*)in_lds)[t] = 0.0f;
    // Load x for step 0.
    for (int t = j; t < R * IN; t += NG) {
        const int r = t / IN, f = t - r * IN;
        in_lds[r][f] = xin[(size_t)(b0 + r) * S_LEN * IN + f];
    }
    __syncthreads();

    float cst = 0.0f;  // cell state (valid for threads with r2 < R)

    for (int s = 0; s < S_LEN; ++s) {
        // ---- gate pre-activations: acc[r] = bias + sum_k w[k]*in[r][k] ----
        float acc[R];
        #pragma unroll
        for (int r = 0; r < R; ++r) acc[r] = bias;
        #pragma unroll
        for (int kc = 0; kc < KP / 4; ++kc) {
            #pragma unroll
            for (int r = 0; r < R; ++r) {
                const float4 v = *(const float4*)&in_lds[r][kc * 4];
                acc[r] = fmaf(v.x, w[kc * 4 + 0], acc[r]);
                acc[r] = fmaf(v.y, w[kc * 4 + 1], acc[r]);
                acc[r] = fmaf(v.z, w[kc * 4 + 2], acc[r]);
                acc[r] = fmaf(v.w, w[kc * 4 + 3], acc[r]);
            }
        }
        // ---- activation (wave-uniform branch: gate 2 = tanh, else sigmoid) ----
        const bool is_tanh = ((j >> 6) == 2);
        #pragma unroll
        for (int r = 0; r < R; ++r)
            g_lds[r][j] = is_tanh ? tanh_f(acc[r]) : sigmoid_f(acc[r]);
        __syncthreads();

        // ---- cell update (threads with r2 < R; others idle here) ----
        if (r2 < R) {
            const float iv = g_lds[r2][jj];
            const float fv = g_lds[r2][NH + jj];
            const float gv = g_lds[r2][2 * NH + jj];
            const float ov = g_lds[r2][3 * NH + jj];
            cst = fmaf(fv, cst, iv * gv);
            const float hv = ov * tanh_f(cst);
            in_lds[r2][IN + jj] = hv;   // h_prev for next step
            if (h_all)
                h_all[((size_t)(b0 + r2) * S_LEN + s) * NH + jj] = hv;
            if (h_last && s == S_LEN - 1)
                h_last[(size_t)(b0 + r2) * NH + jj] = hv;
        }
        // ---- prefetch x for step s+1 ----
        if (s + 1 < S_LEN) {
            for (int t = j; t < R * IN; t += NG) {
                const int r = t / IN, f = t - r * IN;
                in_lds[r][f] =
                    xin[(size_t)(b0 + r) * S_LEN * IN + (size_t)(s + 1) * IN + f];
            }
        }
        __syncthreads();
    }
}

// BatchNorm statistics over the batch dim: one block per feature.
__global__ void bn_stats_kernel(const float* __restrict__ last,   // [B][64]
                                const float* __restrict__ gamma,  // [64]
                                const float* __restrict__ beta,   // [64]
                                float* __restrict__ scale,        // [64]
                                float* __restrict__ shift)        // [64]
{
    const int jf = blockIdx.x;   // feature 0..63
    const int t  = threadIdx.x;  // 256 threads
    float s1 = 0.0f, s2 = 0.0f;
    for (int b = t; b < B_SZ; b += 256) {
        const float v = last[b * NH + jf];
        s1 += v; s2 += v * v;
    }
    #pragma unroll
    for (int off = 32; off > 0; off >>= 1) {
        s1 += __shfl_down(s1, off, 64);
        s2 += __shfl_down(s2, off, 64);
    }
    __shared__ float ls1[4], ls2[4];
    if ((t & 63) == 0) { ls1[t >> 6] = s1; ls2[t >> 6] = s2; }
    __syncthreads();
    if (t == 0) {
        const float S1 = ls1[0] + ls1[1] + ls1[2] + ls1[3];
        const float S2 = ls2[0] + ls2[1] + ls2[2] + ls2[3];
        const float mean = S1 * (1.0f / B_SZ);
        const float var  = S2 * (1.0f / B_SZ) - mean * mean;
        const float sc   = gamma[jf] * rsqrtf(var + 1e-5f);
        scale[jf] = sc;
        shift[jf] = beta[jf] - mean * sc;
    }
}

// Classifier: out[b,o] = sum_j (last[b,j]*scale[j]+shift[j]) * W[o,j] + bias[o]
__global__ void cls_kernel(const float* __restrict__ last,   // [B][64]
                           const float* __restrict__ scale,  // [64]
                           const float* __restrict__ shift,  // [64]
                           const float* __restrict__ W,      // [15][64]
                           const float* __restrict__ bias,   // [15]
                           float* __restrict__ out)          // [B][15]
{
    const int t  = threadIdx.x;        // 256 = 16 rows x 16 cols
    const int o  = t & 15;
    const int ry = t >> 4;
    const int b  = blockIdx.x * 16 + ry;
    if (o >= 15) return;
    float acc = bias[o];
    #pragma unroll
    for (int jf = 0; jf < NH; ++jf) {
        const float nv = fmaf(last[b * NH + jf], scale[jf], shift[jf]);
        acc = fmaf(nv, W[o * NH + jf], acc);
    }
    out[b * 15 + o] = acc;
}

extern "C" void kernel_launch(void* const* d_in, const int* in_sizes, int n_in,
                              void* d_out, int out_size, void* d_ws, size_t ws_size,
                              hipStream_t stream) {
    const float* X      = (const float*)d_in[0];   // [1024][512][18]
    const float* W_ih0  = (const float*)d_in[1];   // [256][18]
    const float* W_hh0  = (const float*)d_in[2];   // [256][64]
    const float* b_ih0  = (const float*)d_in[3];
    const float* b_hh0  = (const float*)d_in[4];
    const float* W_ih1  = (const float*)d_in[5];   // [256][64]
    const float* W_hh1  = (const float*)d_in[6];   // [256][64]
    const float* b_ih1  = (const float*)d_in[7];
    const float* b_hh1  = (const float*)d_in[8];
    const float* gamma  = (const float*)d_in[9];
    const float* beta   = (const float*)d_in[10];
    const float* cls_W  = (const float*)d_in[11];  // [15][64]
    const float* cls_b  = (const float*)d_in[12];
    float* out = (float*)d_out;                    // [1024][15]

    // Workspace layout (needs ~128.25 MB):
    //   h1    : [B][S][64] fp32 = 134217728 B
    //   last  : [B][64]         =    262144 B
    //   scale : [64], shift : [64]
    float* h1    = (float*)d_ws;
    float* last  = h1 + (size_t)B_SZ * S_LEN * NH;
    float* scale = last + (size_t)B_SZ * NH;
    float* shift = scale + NH;

    constexpr int R = 2;  // batch rows per block
    // Layer 0: input F=18, writes all h1 timesteps.
    lstm_layer_kernel<18, R><<<B_SZ / R, 256, 0, stream>>>(
        X, W_ih0, W_hh0, b_ih0, b_hh0, h1, nullptr);
    // Layer 1: input = h1 (64), writes only final hidden state.
    lstm_layer_kernel<64, R><<<B_SZ / R, 256, 0, stream>>>(
        h1, W_ih1, W_hh1, b_ih1, b_hh1, nullptr, last);
    // BatchNorm stats (over batch) -> per-feature scale/shift.
    bn_stats_kernel<<<NH, 256, 0, stream>>>(last, gamma, beta, scale, shift);
    // Classifier.
    cls_kernel<<<B_SZ / 16, 256, 0, stream>>>(last, scale, shift, cls_W, cls_b, out);
}

// Round 4
// 1797.302 us; speedup vs baseline: 1.2369x; 1.2369x over previous
//
#include <hip/hip_runtime.h>
#include <hip/hip_bf16.h>
#include <cstdint>
#include <cstddef>

// Problem constants: B=1024, S=512, F=18, H=64, O=15
#define B_SZ  1024
#define S_LEN 512
#define NH    64
#define NG    256   // 4*H gate rows

typedef float f32x2 __attribute__((ext_vector_type(2)));
typedef float f32x4 __attribute__((ext_vector_type(4)));

__device__ __forceinline__ float sigmoid_f(float x) {
    return __fdividef(1.0f, 1.0f + __expf(-x));
}
__device__ __forceinline__ float tanh_f(float x) {
    return 1.0f - __fdividef(2.0f, __expf(2.0f * x) + 1.0f);
}

// v_pk_fma_f32: acc.xy += a.xy * b.xy  (2 fp32 FMA per lane per instr)
__device__ __forceinline__ void pk_fma(f32x2& acc, f32x2 a, f32x2 b) {
    asm("v_pk_fma_f32 %0, %1, %2, %0" : "+v"(acc) : "v"(a), "v"(b));
}

// One LSTM layer scan, packed-fp32, K-split x2, spill-free.
//  - 512 threads (8 waves), R=2 batch rows per block, grid = 512 blocks
//    (2 blocks/CU -> 16 waves/CU).
//  - Thread t: gate row g = t>>1 (0..255), K-half hf = t&1. Owns
//    w[KH] <= 64 VGPRs of the padded [x | h | 0] weight row.
//  - Per step: dot via v_pk_fma_f32 on float4 LDS broadcast reads
//    (2 distinct addrs/wave -> 32-lane broadcast each, conflict-free);
//    cross-half reduce via __shfl_xor(1); wave-uniform activation branch;
//    cell update on waves 0-1; x-prefetch in regs on waves 6-7 (T14 split).
template<int KIN>
__global__ __launch_bounds__(512, 4) void lstm_pk(
    const float* __restrict__ xin,    // [B][S][KIN]
    const float* __restrict__ W_ih,   // [256][KIN]
    const float* __restrict__ W_hh,   // [256][64]
    const float* __restrict__ b_ih,   // [256]
    const float* __restrict__ b_hh,   // [256]
    float* __restrict__ h_all,        // [B][S][64] or nullptr
    float* __restrict__ h_last)       // [B][64]    or nullptr
{
    constexpr int R     = 2;
    constexpr int K     = KIN + NH;
    constexpr int KP    = (K + 15) & ~15;   // 96 (L0) / 128 (L1)
    constexpr int KH    = KP / 2;           // 48 / 64 floats per half
    constexpr int CH    = KH / 4;           // float4 chunks per half
    constexpr int NXL   = R * KIN;          // x loads per step
    constexpr int XT0   = 512 - NXL;        // x-loader threads start here

    __shared__ float in_lds[R][KP];         // [x_t | h_prev | zero pad]
    __shared__ float g_lds[R][NG];          // activated gates

    const int t  = threadIdx.x;
    const int g  = t >> 1;                  // gate row 0..255
    const int hf = t & 1;                   // K-half
    const int b0 = blockIdx.x * R;

    // ---- persistent weights: this thread's K-half of gate row g ----
    f32x2 w2[KH / 2];
    #pragma unroll
    for (int k = 0; k < KH; ++k) {
        const int gk = hf * KH + k;         // position in padded [x|h|0]
        float wv;
        if (gk < KIN)      wv = W_ih[g * KIN + gk];
        else if (gk < K)   wv = W_hh[g * NH + (gk - KIN)];
        else               wv = 0.0f;
        w2[k >> 1][k & 1] = wv;
    }
    const float bias = b_ih[g] + b_hh[g];

    // ---- init LDS (no divergent barriers): zero, barrier, x0, barrier ----
    if (t < R * KP) ((float*)in_lds)[t] = 0.0f;
    __syncthreads();
    if (t >= XT0) {
        const int xt = t - XT0;             // 0..NXL-1
        const int r = xt / KIN, f = xt - r * KIN;
        in_lds[r][f] = xin[(size_t)(b0 + r) * S_LEN * KIN + f];
    }
    __syncthreads();

    float cst = 0.0f;                       // cell state (waves 0-1 only)
    const int base = hf * KH;

    for (int s = 0; s < S_LEN; ++s) {
        // ---- (1) issue x prefetch for s+1 early (hides HBM latency) ----
        float xreg = 0.0f;
        if (t >= XT0 && s + 1 < S_LEN) {
            const int xt = t - XT0;
            const int r = xt / KIN, f = xt - r * KIN;
            xreg = xin[(size_t)(b0 + r) * S_LEN * KIN + (size_t)(s + 1) * KIN + f];
        }

        // ---- (2) half-dot via packed fp32 FMA ----
        f32x2 acc[R];
        #pragma unroll
        for (int r = 0; r < R; ++r) acc[r] = (f32x2){hf == 0 ? bias : 0.0f, 0.0f};
        #pragma unroll
        for (int c = 0; c < CH; ++c) {
            #pragma unroll
            for (int r = 0; r < R; ++r) {
                const f32x4 v = *(const f32x4*)&in_lds[r][base + 4 * c];
                const f32x2 vlo = __builtin_shufflevector(v, v, 0, 1);
                const f32x2 vhi = __builtin_shufflevector(v, v, 2, 3);
                pk_fma(acc[r], w2[2 * c],     vlo);
                pk_fma(acc[r], w2[2 * c + 1], vhi);
            }
        }

        // ---- (3) reduce + activation (wave-uniform gate type) ----
        const bool is_tanh = ((g >> 6) == 2);
        #pragma unroll
        for (int r = 0; r < R; ++r) {
            float d = acc[r].x + acc[r].y;
            d += __shfl_xor(d, 1);          // combine K-halves
            g_lds[r][g] = is_tanh ? tanh_f(d) : sigmoid_f(d);
        }
        __syncthreads();

        // ---- (4) cell update: waves 0-1 (t<128), wave-uniform branch ----
        if (t < R * NH) {
            const int r  = t >> 6;
            const int jj = t & 63;
            const float iv = g_lds[r][jj];
            const float fv = g_lds[r][NH + jj];
            const float gv = g_lds[r][2 * NH + jj];
            const float ov = g_lds[r][3 * NH + jj];
            cst = fmaf(fv, cst, iv * gv);
            const float hv = ov * tanh_f(cst);
            in_lds[r][KIN + jj] = hv;       // h_prev for next step
            if (h_all)
                h_all[((size_t)(b0 + r) * S_LEN + s) * NH + jj] = hv;
            if (h_last && s == S_LEN - 1)
                h_last[(size_t)(b0 + r) * NH + jj] = hv;
        }
        // ---- (5) commit prefetched x for s+1: waves 6-7 ----
        if (t >= XT0 && s + 1 < S_LEN) {
            const int xt = t - XT0;
            const int r = xt / KIN, f = xt - r * KIN;
            in_lds[r][f] = xreg;
        }
        __syncthreads();
    }
}

// BatchNorm statistics over the batch dim: one block per feature.
__global__ void bn_stats_kernel(const float* __restrict__ last,   // [B][64]
                                const float* __restrict__ gamma,  // [64]
                                const float* __restrict__ beta,   // [64]
                                float* __restrict__ scale,        // [64]
                                float* __restrict__ shift)        // [64]
{
    const int jf = blockIdx.x;
    const int t  = threadIdx.x;  // 256 threads
    float s1 = 0.0f, s2 = 0.0f;
    for (int b = t; b < B_SZ; b += 256) {
        const float v = last[b * NH + jf];
        s1 += v; s2 += v * v;
    }
    #pragma unroll
    for (int off = 32; off > 0; off >>= 1) {
        s1 += __shfl_down(s1, off, 64);
        s2 += __shfl_down(s2, off, 64);
    }
    __shared__ float ls1[4], ls2[4];
    if ((t & 63) == 0) { ls1[t >> 6] = s1; ls2[t >> 6] = s2; }
    __syncthreads();
    if (t == 0) {
        const float S1 = ls1[0] + ls1[1] + ls1[2] + ls1[3];
        const float S2 = ls2[0] + ls2[1] + ls2[2] + ls2[3];
        const float mean = S1 * (1.0f / B_SZ);
        const float var  = S2 * (1.0f / B_SZ) - mean * mean;
        const float sc   = gamma[jf] * rsqrtf(var + 1e-5f);
        scale[jf] = sc;
        shift[jf] = beta[jf] - mean * sc;
    }
}

// Classifier: out[b,o] = sum_j (last[b,j]*scale[j]+shift[j]) * W[o,j] + bias[o]
__global__ void cls_kernel(const float* __restrict__ last,   // [B][64]
                           const float* __restrict__ scale,  // [64]
                           const float* __restrict__ shift,  // [64]
                           const float* __restrict__ W,      // [15][64]
                           const float* __restrict__ bias,   // [15]
                           float* __restrict__ out)          // [B][15]
{
    const int t  = threadIdx.x;        // 256 = 16 rows x 16 cols
    const int o  = t & 15;
    const int ry = t >> 4;
    const int b  = blockIdx.x * 16 + ry;
    if (o >= 15) return;
    float acc = bias[o];
    #pragma unroll
    for (int jf = 0; jf < NH; ++jf) {
        const float nv = fmaf(last[b * NH + jf], scale[jf], shift[jf]);
        acc = fmaf(nv, W[o * NH + jf], acc);
    }
    out[b * 15 + o] = acc;
}

extern "C" void kernel_launch(void* const* d_in, const int* in_sizes, int n_in,
                              void* d_out, int out_size, void* d_ws, size_t ws_size,
                              hipStream_t stream) {
    const float* X      = (const float*)d_in[0];   // [1024][512][18]
    const float* W_ih0  = (const float*)d_in[1];   // [256][18]
    const float* W_hh0  = (const float*)d_in[2];   // [256][64]
    const float* b_ih0  = (const float*)d_in[3];
    const float* b_hh0  = (const float*)d_in[4];
    const float* W_ih1  = (const float*)d_in[5];   // [256][64]
    const float* W_hh1  = (const float*)d_in[6];   // [256][64]
    const float* b_ih1  = (const float*)d_in[7];
    const float* b_hh1  = (const float*)d_in[8];
    const float* gamma  = (const float*)d_in[9];
    const float* beta   = (const float*)d_in[10];
    const float* cls_W  = (const float*)d_in[11];  // [15][64]
    const float* cls_b  = (const float*)d_in[12];
    float* out = (float*)d_out;                    // [1024][15]

    // Workspace: h1 [B][S][64] f32 (128MB) + last [B][64] + scale/shift
    float* h1    = (float*)d_ws;
    float* last  = h1 + (size_t)B_SZ * S_LEN * NH;
    float* scale = last + (size_t)B_SZ * NH;
    float* shift = scale + NH;

    constexpr int R = 2;
    lstm_pk<18><<<B_SZ / R, 512, 0, stream>>>(
        X, W_ih0, W_hh0, b_ih0, b_hh0, h1, nullptr);
    lstm_pk<64><<<B_SZ / R, 512, 0, stream>>>(
        h1, W_ih1, W_hh1, b_ih1, b_hh1, nullptr, last);
    bn_stats_kernel<<<NH, 256, 0, stream>>>(last, gamma, beta, scale, shift);
    cls_kernel<<<B_SZ / 16, 256, 0, stream>>>(last, scale, shift, cls_W, cls_b, out);
}

// Round 5
// 1689.955 us; speedup vs baseline: 1.3155x; 1.0635x over previous
//
#include <hip/hip_runtime.h>
#include <cstdint>
#include <cstddef>

// Problem constants: B=1024, S=512, F=18, H=64, O=15
#define B_SZ  1024
#define S_LEN 512
#define NH    64

typedef float f32x2 __attribute__((ext_vector_type(2)));
typedef float f32x4 __attribute__((ext_vector_type(4)));

__device__ __forceinline__ float sigmoid_f(float x) {
    return __fdividef(1.0f, 1.0f + __expf(-x));
}
__device__ __forceinline__ float tanh_f(float x) {
    return 1.0f - __fdividef(2.0f, __expf(2.0f * x) + 1.0f);
}
// v_pk_fma_f32: acc.xy += a.xy * b.xy (2 fp32 FMA / lane / instr)
__device__ __forceinline__ void pk_fma(f32x2& acc, f32x2 a, f32x2 b) {
    asm("v_pk_fma_f32 %0, %1, %2, %0" : "+v"(acc) : "v"(a), "v"(b));
}
// x += (x from lane^XOR) via DPP quad_perm (VALU pipe, NOT the LDS pipe).
// 0xB1 = [1,0,3,2] = xor1; 0x4E = [2,3,0,1] = xor2.
template<int CTRL>
__device__ __forceinline__ float dpp_add(float x) {
    int s = __builtin_amdgcn_update_dpp(0, __float_as_int(x), CTRL, 0xF, 0xF, true);
    return x + __int_as_float(s);
}

// LSTM scan, register-gate-blocked:
//   T=256 threads, 1 batch row per block, grid = B blocks.
//   Thread t -> (gg = t>>3, kc = t&7): owns 8 gate rows g = 8*gg + j
//   (j=0..7) restricted to K-chunk kc (CH = KP/8 floats of [x|h|pad]).
//   Weights: 8 x CH floats in VGPRs (96/128 regs). Per step:
//     phase A: NB128 ds_read_b128 (bank-staggered, conflict-free broadcast
//              to 8-lane groups) -> 8*CH FMAs via pk_fma -> per-quad DPP
//              butterfly (xor1+xor2) -> each lane writes 2 partials to
//              g_part at lane-contiguous words (t, t+260).
//     phase B: wave 0 (t<64): gate finisher: 8 partial reads (2-way banks),
//              +bias, sigmoid/tanh, c/h update, h -> in_lds (+global).
//              threads [64,64+KIN): commit x_{s+1} prefetched in phase A.
//   LDS layout of input row: chunk kc at words kc*CROW; CROW = CH+STAG
//   chosen so the 8 chunk bases hit distinct bank groups (CH=12: 12kc%32,
//   CH=16: 20kc%32 — both permutations of {0,4,...,28}).
template<int KIN>
__global__ __launch_bounds__(256, 2) void lstm_scan(
    const float* __restrict__ xin,    // [B][S][KIN]
    const float* __restrict__ W_ih,   // [256][KIN]
    const float* __restrict__ W_hh,   // [256][64]
    const float* __restrict__ b_ih,   // [256]
    const float* __restrict__ b_hh,   // [256]
    float* __restrict__ h_all,        // [B][S][64] or nullptr
    float* __restrict__ h_last)       // [B][64]    or nullptr
{
    constexpr int K     = KIN + NH;            // 82 / 128
    constexpr int KP    = (K + 31) & ~31;      // 96 / 128
    constexpr int CH    = KP / 8;              // 12 / 16
    constexpr int STAG  = (CH % 8 == 0) ? 4 : 0;
    constexpr int CROW  = CH + STAG;           // 12 / 20
    constexpr int NB128 = CH / 4;              // 3 / 4

    __shared__ __align__(16) float in_lds[8 * CROW];
    __shared__ float g_part[520];              // 256 gates x 2 partials (+pad)

    const int t  = threadIdx.x;
    const int kc = t & 7;
    const int gg = t >> 3;                     // 0..31
    const int b  = blockIdx.x;

    // word position of logical input element f in the staggered layout
    auto WPOS = [](int f) { return (f / CH) * CROW + (f % CH); };

    // ---- persistent weights: 8 gates x CH floats (as f32x2 pairs) ----
    f32x2 w2[8][CH / 2];
    #pragma unroll
    for (int j = 0; j < 8; ++j) {
        const int g = 8 * gg + j;
        #pragma unroll
        for (int i = 0; i < CH; ++i) {
            const int k = kc * CH + i;
            float wv;
            if (k < KIN)    wv = W_ih[g * KIN + k];
            else if (k < K) wv = W_hh[g * NH + (k - KIN)];
            else            wv = 0.0f;
            w2[j][i >> 1][i & 1] = wv;
        }
    }

    // ---- finisher-wave per-thread state (t < 64): biases + cell state ----
    float bias_i = 0, bias_f = 0, bias_g = 0, bias_o = 0, cst = 0.0f;
    if (t < NH) {
        bias_i = b_ih[0 * NH + t] + b_hh[0 * NH + t];
        bias_f = b_ih[1 * NH + t] + b_hh[1 * NH + t];
        bias_g = b_ih[2 * NH + t] + b_hh[2 * NH + t];
        bias_o = b_ih[3 * NH + t] + b_hh[3 * NH + t];
    }

    // ---- init: zero input row (h0 = 0, pads stay 0), load x_0 ----
    if (t < 8 * CROW) in_lds[t] = 0.0f;
    __syncthreads();
    if (t >= 64 && t < 64 + KIN)
        in_lds[WPOS(t - 64)] = xin[(size_t)b * S_LEN * KIN + (t - 64)];
    __syncthreads();

    const int ib = kc * CROW;                  // this thread's chunk base

    for (int s = 0; s < S_LEN; ++s) {
        // -- issue x_{s+1} prefetch early (committed in phase B) --
        float xreg = 0.0f;
        if (t >= 64 && t < 64 + KIN && s + 1 < S_LEN)
            xreg = xin[(size_t)b * S_LEN * KIN + (size_t)(s + 1) * KIN + (t - 64)];

        // -- phase A: 8-gate chunk dot --
        f32x2 acc2[8] = {};
        #pragma unroll
        for (int ii = 0; ii < NB128; ++ii) {
            const f32x4 v = *reinterpret_cast<const f32x4*>(&in_lds[ib + 4 * ii]);
            const f32x2 vlo = {v.x, v.y};
            const f32x2 vhi = {v.z, v.w};
            #pragma unroll
            for (int j = 0; j < 8; ++j) {
                pk_fma(acc2[j], w2[j][2 * ii],     vlo);
                pk_fma(acc2[j], w2[j][2 * ii + 1], vhi);
            }
        }
        float a[8];
        #pragma unroll
        for (int j = 0; j < 8; ++j) a[j] = acc2[j].x + acc2[j].y;
        // per-quad butterfly: after xor1+xor2 each lane has its quad's
        // 4-lane sum for all 8 gates (quad = kc&4 half of the kc-group)
        #pragma unroll
        for (int j = 0; j < 8; ++j) a[j] = dpp_add<0xB1>(a[j]);
        #pragma unroll
        for (int j = 0; j < 8; ++j) a[j] = dpp_add<0x4E>(a[j]);
        // lane (gg,kc) publishes gate 8*gg+(kc&3) (lo) and +4 (hi),
        // partial index h = kc>>2; words t and t+260 are lane-contiguous.
        {
            const int sel = kc & 3;
            const float q01 = (sel & 1) ? a[1] : a[0];
            const float q23 = (sel & 1) ? a[3] : a[2];
            const float lo  = (sel & 2) ? q23 : q01;
            const float q45 = (sel & 1) ? a[5] : a[4];
            const float q67 = (sel & 1) ? a[7] : a[6];
            const float hi  = (sel & 2) ? q67 : q45;
            g_part[t]       = lo;
            g_part[t + 260] = hi;
        }
        __syncthreads();

        // -- phase B --
        if (t < NH) {
            // gate G = 64*c + jj, partial h at word:
            //   64*c + 8*(jj>>3) + (jj&3) + 4*h + (jj&4 ? 260 : 0)
            const int jj = t;
            const int wb = 8 * (jj >> 3) + (jj & 3) + ((jj & 4) ? 260 : 0);
            const float pi = g_part[0 * 64 + wb] + g_part[0 * 64 + wb + 4] + bias_i;
            const float pf = g_part[1 * 64 + wb] + g_part[1 * 64 + wb + 4] + bias_f;
            const float pg = g_part[2 * 64 + wb] + g_part[2 * 64 + wb + 4] + bias_g;
            const float po = g_part[3 * 64 + wb] + g_part[3 * 64 + wb + 4] + bias_o;
            const float iv = sigmoid_f(pi);
            const float fv = sigmoid_f(pf);
            const float gv = tanh_f(pg);
            const float ov = sigmoid_f(po);
            cst = fmaf(fv, cst, iv * gv);
            const float hv = ov * tanh_f(cst);
            in_lds[WPOS(KIN + jj)] = hv;       // h_prev for next step
            if (h_all)
                h_all[((size_t)b * S_LEN + s) * NH + jj] = hv;
            if (h_last && s == S_LEN - 1)
                h_last[(size_t)b * NH + jj] = hv;
        } else if (t < 64 + KIN) {
            if (s + 1 < S_LEN) in_lds[WPOS(t - 64)] = xreg;
        }
        __syncthreads();
    }
}

// BatchNorm statistics over the batch dim: one block per feature.
__global__ void bn_stats_kernel(const float* __restrict__ last,   // [B][64]
                                const float* __restrict__ gamma,  // [64]
                                const float* __restrict__ beta,   // [64]
                                float* __restrict__ scale,        // [64]
                                float* __restrict__ shift)        // [64]
{
    const int jf = blockIdx.x;
    const int t  = threadIdx.x;  // 256 threads
    float s1 = 0.0f, s2 = 0.0f;
    for (int b = t; b < B_SZ; b += 256) {
        const float v = last[b * NH + jf];
        s1 += v; s2 += v * v;
    }
    #pragma unroll
    for (int off = 32; off > 0; off >>= 1) {
        s1 += __shfl_down(s1, off, 64);
        s2 += __shfl_down(s2, off, 64);
    }
    __shared__ float ls1[4], ls2[4];
    if ((t & 63) == 0) { ls1[t >> 6] = s1; ls2[t >> 6] = s2; }
    __syncthreads();
    if (t == 0) {
        const float S1 = ls1[0] + ls1[1] + ls1[2] + ls1[3];
        const float S2 = ls2[0] + ls2[1] + ls2[2] + ls2[3];
        const float mean = S1 * (1.0f / B_SZ);
        const float var  = S2 * (1.0f / B_SZ) - mean * mean;
        const float sc   = gamma[jf] * rsqrtf(var + 1e-5f);
        scale[jf] = sc;
        shift[jf] = beta[jf] - mean * sc;
    }
}

// Classifier: out[b,o] = sum_j (last[b,j]*scale[j]+shift[j]) * W[o,j] + bias[o]
__global__ void cls_kernel(const float* __restrict__ last,   // [B][64]
                           const float* __restrict__ scale,  // [64]
                           const float* __restrict__ shift,  // [64]
                           const float* __restrict__ W,      // [15][64]
                           const float* __restrict__ bias,   // [15]
                           float* __restrict__ out)          // [B][15]
{
    const int t  = threadIdx.x;        // 256 = 16 rows x 16 cols
    const int o  = t & 15;
    const int ry = t >> 4;
    const int b  = blockIdx.x * 16 + ry;
    if (o >= 15) return;
    float acc = bias[o];
    #pragma unroll
    for (int jf = 0; jf < NH; ++jf) {
        const float nv = fmaf(last[b * NH + jf], scale[jf], shift[jf]);
        acc = fmaf(nv, W[o * NH + jf], acc);
    }
    out[b * 15 + o] = acc;
}

extern "C" void kernel_launch(void* const* d_in, const int* in_sizes, int n_in,
                              void* d_out, int out_size, void* d_ws, size_t ws_size,
                              hipStream_t stream) {
    const float* X      = (const float*)d_in[0];   // [1024][512][18]
    const float* W_ih0  = (const float*)d_in[1];   // [256][18]
    const float* W_hh0  = (const float*)d_in[2];   // [256][64]
    const float* b_ih0  = (const float*)d_in[3];
    const float* b_hh0  = (const float*)d_in[4];
    const float* W_ih1  = (const float*)d_in[5];   // [256][64]
    const float* W_hh1  = (const float*)d_in[6];   // [256][64]
    const float* b_ih1  = (const float*)d_in[7];
    const float* b_hh1  = (const float*)d_in[8];
    const float* gamma  = (const float*)d_in[9];
    const float* beta   = (const float*)d_in[10];
    const float* cls_W  = (const float*)d_in[11];  // [15][64]
    const float* cls_b  = (const float*)d_in[12];
    float* out = (float*)d_out;                    // [1024][15]

    // Workspace: h1 [B][S][64] f32 (128MB) + last [B][64] + scale/shift
    float* h1    = (float*)d_ws;
    float* last  = h1 + (size_t)B_SZ * S_LEN * NH;
    float* scale = last + (size_t)B_SZ * NH;
    float* shift = scale + NH;

    lstm_scan<18><<<B_SZ, 256, 0, stream>>>(
        X, W_ih0, W_hh0, b_ih0, b_hh0, h1, nullptr);
    lstm_scan<64><<<B_SZ, 256, 0, stream>>>(
        h1, W_ih1, W_hh1, b_ih1, b_hh1, nullptr, last);
    bn_stats_kernel<<<NH, 256, 0, stream>>>(last, gamma, beta, scale, shift);
    cls_kernel<<<B_SZ / 16, 256, 0, stream>>>(last, scale, shift, cls_W, cls_b, out);
}